// Round 2
// baseline (838.498 us; speedup 1.0000x reference)
//
#include <hip/hip_runtime.h>

typedef unsigned int u32;

// B=65536, D=256, H=512, C=10, P=10, HP=128. All float tensors fp32; rdd int32.
// Fully fused: per 16-row block: target net (fp32) -> logits -> top-2 bitmap ->
// gated patch nets (~1.1 active/row vs 10 dense in reference) -> fp32 out.

__global__ __launch_bounds__(256) void netsum_kernel(
    const float* __restrict__ x,   const float* __restrict__ Wt1, const float* __restrict__ bt1,
    const float* __restrict__ Wt2, const float* __restrict__ bt2,
    const float* __restrict__ Wp1, const float* __restrict__ bp1,
    const float* __restrict__ Wp2, const float* __restrict__ bp2,
    const int* __restrict__ rdd, float* __restrict__ out)
{
    __shared__ float xs[16][256];    // x tile
    __shared__ float hbuf[16][513];  // relu(x@Wt1+bt1), padded vs bank conflicts
    __shared__ float lg[16][10];     // logits incl bt2
    __shared__ u32 bmp[16];          // bitmap per row

    const int t = threadIdx.x;
    const int lane = t & 63;
    const int w = t >> 6;            // wave id 0..3, handles rows w*4..w*4+3
    const int row0 = blockIdx.x * 16;

    // ---- stage x: 16 rows x 256 fp32 -> LDS (thread t: row t/16, 16 elems) ----
    {
        int r = t >> 4, seg = t & 15;
        const float4* src = (const float4*)(x + (size_t)(row0 + r) * 256 + seg * 16);
        float4* dst = (float4*)&xs[r][seg * 16];
        #pragma unroll
        for (int k = 0; k < 4; ++k) dst[k] = src[k];
    }
    __syncthreads();

    // ---- target layer 1: 4 rows/wave, 8 cols/lane (cols lane*8..+7), K=256 ----
    {
        float acc[4][8];
        #pragma unroll
        for (int r=0;r<4;++r)
            #pragma unroll
            for (int j=0;j<8;++j) acc[r][j]=0.f;

        const int col0 = lane * 8;
        const float* wcol = Wt1 + col0;
        for (int d = 0; d < 256; ++d) {
            float4 wa = *(const float4*)(wcol + (size_t)d * 512);
            float4 wb = *(const float4*)(wcol + (size_t)d * 512 + 4);
            float wf[8] = {wa.x, wa.y, wa.z, wa.w, wb.x, wb.y, wb.z, wb.w};
            #pragma unroll
            for (int r=0;r<4;++r) {
                float xv = xs[w*4+r][d];
                #pragma unroll
                for (int j=0;j<8;++j) acc[r][j] += xv * wf[j];
            }
        }
        float4 ba = *(const float4*)(bt1 + col0);
        float4 bb = *(const float4*)(bt1 + col0 + 4);
        float bfv[8] = {ba.x, ba.y, ba.z, ba.w, bb.x, bb.y, bb.z, bb.w};
        #pragma unroll
        for (int r=0;r<4;++r)
            #pragma unroll
            for (int j=0;j<8;++j) {
                float v = acc[r][j] + bfv[j];
                hbuf[w*4+r][col0+j] = v > 0.f ? v : 0.f;
            }
    }
    __syncthreads();

    // ---- target layer 2: 16 lanes per row, xor-shuffle reduce, fp32 logits ----
    {
        int row = t >> 4, tid = t & 15;
        float acc2[10];
        #pragma unroll
        for (int c=0;c<10;++c) acc2[c]=0.f;
        for (int j = tid; j < 512; j += 16) {
            float hv = hbuf[row][j];
            const float* w2 = Wt2 + j*10;
            #pragma unroll
            for (int c=0;c<10;++c) acc2[c] += hv * w2[c];
        }
        #pragma unroll
        for (int c=0;c<10;++c) {
            #pragma unroll
            for (int off=8; off>0; off>>=1) acc2[c] += __shfl_xor(acc2[c], off, 64);
        }
        if (tid < 10) lg[row][tid] = acc2[tid] + bt2[tid];
    }
    __syncthreads();

    // ---- top-2 + bitmap per row (threads 0..15) ----
    if (t < 16) {
        float best = -1e30f; int i0 = 0;
        #pragma unroll
        for (int c=0;c<10;++c){ float v = lg[t][c]; if (v > best){best=v;i0=c;} }
        float b2 = -1e30f; int i1 = 0;
        #pragma unroll
        for (int c=0;c<10;++c){ if (c==i0) continue; float v = lg[t][c]; if (v > b2){b2=v;i1=c;} }
        u32 exact=0, fb=0;
        #pragma unroll
        for (int p=0;p<10;++p){
            int a = rdd[2*p], b = rdd[2*p+1];
            if (i0==a && i1==b) exact |= 1u<<p;
            if (i0==a)          fb    |= 1u<<p;
        }
        bmp[t] = exact ? exact : fb;
    }
    __syncthreads();

    // ---- patches (gated) + combine: wave w does rows w*4..+3, 2 HP-cols/lane ----
    for (int r = 0; r < 4; ++r) {
        const int row = w*4 + r;
        u32 bits = bmp[row];          // wave-uniform
        float p2[10];
        #pragma unroll
        for (int c=0;c<10;++c) p2[c]=0.f;
        float bsum = 0.f;
        const int li = lane < 10 ? lane : 0;
        const int col0 = lane*2;
        while (bits) {
            int p = __ffs(bits) - 1;
            bits &= bits - 1;
            float h0=0.f, h1=0.f;
            const float* wb = Wp1 + (size_t)p*256*128 + col0;
            for (int d=0; d<256; ++d) {
                float2 wv = *(const float2*)(wb + (size_t)d*128);
                float xv = xs[row][d];
                h0 += xv * wv.x;
                h1 += xv * wv.y;
            }
            float2 bv = *(const float2*)(bp1 + p*128 + col0);
            h0 += bv.x; h1 += bv.y;
            h0 = h0>0.f?h0:0.f; h1 = h1>0.f?h1:0.f;
            const float* w2r = Wp2 + ((size_t)p*128 + col0)*10;
            #pragma unroll
            for (int c=0;c<10;++c)
                p2[c] += h0 * w2r[c] + h1 * w2r[10+c];
            bsum += bp2[p*10 + li];
        }
        // butterfly reduce each of the 10 sums across the wave; lane c keeps c's total
        float outv = 0.f;
        #pragma unroll
        for (int c=0;c<10;++c) {
            float v = p2[c];
            #pragma unroll
            for (int off=32; off>0; off>>=1) v += __shfl_xor(v, off, 64);
            if (lane == c) outv = v;
        }
        if (lane < 10) {
            out[(size_t)(row0+row)*10 + lane] = lg[row][lane] + outv + bsum;
        }
    }
}

extern "C" void kernel_launch(void* const* d_in, const int* in_sizes, int n_in,
                              void* d_out, int out_size, void* d_ws, size_t ws_size,
                              hipStream_t stream) {
    const float* x   = (const float*)d_in[0];
    const float* Wt1 = (const float*)d_in[1];
    const float* bt1 = (const float*)d_in[2];
    const float* Wt2 = (const float*)d_in[3];
    const float* bt2 = (const float*)d_in[4];
    const float* Wp1 = (const float*)d_in[5];
    const float* bp1 = (const float*)d_in[6];
    const float* Wp2 = (const float*)d_in[7];
    const float* bp2 = (const float*)d_in[8];
    const int* rdd = (const int*)d_in[9];
    float* out = (float*)d_out;

    dim3 grid(65536 / 16), block(256);
    hipLaunchKernelGGL(netsum_kernel, grid, block, 0, stream,
                       x, Wt1, bt1, Wt2, bt2, Wp1, bp1, Wp2, bp2, rdd, out);
}